// Round 8
// baseline (5364.157 us; speedup 1.0000x reference)
//
#include <hip/hip_runtime.h>
#include <cmath>

#define B_ 16
#define T_ 2048
#define D_ 512
#define H_ 512

typedef __attribute__((ext_vector_type(4))) unsigned int uint4v;

// ---------------------------------------------------------------------------
// Phase 1: XW[m, n] = x[m, :] @ W_xh[:, n] + bias[n] -> d_out.
// M = 32768, K = 512, N = 512. fp32, 128x128 tile, 8x8 acc per thread.
// ---------------------------------------------------------------------------
__global__ __launch_bounds__(256) void gemm_xw(
    const float* __restrict__ x,     // [M, K]
    const float* __restrict__ Wxh,   // [K, N]
    const float* __restrict__ bias,  // [N]
    float* __restrict__ out)         // [M, N]
{
    const int tid = threadIdx.x;
    const int n0 = blockIdx.x * 128;
    const int m0 = blockIdx.y * 128;

    __shared__ float As[8][132];  // [k][m], +4 pad
    __shared__ float Bs[8][132];  // [k][n]

    const int tx = tid & 15, ty = tid >> 4;
    float acc[8][8] = {};

    const int arow = tid >> 1;
    const int akq  = (tid & 1) * 4;
    const int brow = tid >> 5;
    const int bcol = (tid & 31) * 4;

    for (int k0 = 0; k0 < D_; k0 += 8) {
        float4 a4 = *(const float4*)(x + (size_t)(m0 + arow) * D_ + k0 + akq);
        float4 b4 = *(const float4*)(Wxh + (size_t)(k0 + brow) * H_ + n0 + bcol);
        __syncthreads();
        As[akq + 0][arow] = a4.x;
        As[akq + 1][arow] = a4.y;
        As[akq + 2][arow] = a4.z;
        As[akq + 3][arow] = a4.w;
        *(float4*)(&Bs[brow][bcol]) = b4;
        __syncthreads();
#pragma unroll
        for (int kk = 0; kk < 8; ++kk) {
            float4 a0 = *(const float4*)(&As[kk][ty * 8]);
            float4 a1 = *(const float4*)(&As[kk][ty * 8 + 4]);
            float4 b0 = *(const float4*)(&Bs[kk][tx * 8]);
            float4 b1 = *(const float4*)(&Bs[kk][tx * 8 + 4]);
            float a_[8] = {a0.x, a0.y, a0.z, a0.w, a1.x, a1.y, a1.z, a1.w};
            float b_[8] = {b0.x, b0.y, b0.z, b0.w, b1.x, b1.y, b1.z, b1.w};
#pragma unroll
            for (int i = 0; i < 8; ++i)
#pragma unroll
                for (int j = 0; j < 8; ++j) acc[i][j] += a_[i] * b_[j];
        }
    }

    const float4 bv0 = *(const float4*)(bias + n0 + tx * 8);
    const float4 bv1 = *(const float4*)(bias + n0 + tx * 8 + 4);
    const float bb[8] = {bv0.x, bv0.y, bv0.z, bv0.w, bv1.x, bv1.y, bv1.z, bv1.w};
#pragma unroll
    for (int i = 0; i < 8; ++i) {
        const int m = m0 + ty * 8 + i;
        float4 o0, o1;
        o0.x = acc[i][0] + bb[0]; o0.y = acc[i][1] + bb[1];
        o0.z = acc[i][2] + bb[2]; o0.w = acc[i][3] + bb[3];
        o1.x = acc[i][4] + bb[4]; o1.y = acc[i][5] + bb[5];
        o1.z = acc[i][6] + bb[6]; o1.w = acc[i][7] + bb[7];
        *(float4*)(out + (size_t)m * H_ + n0 + tx * 8)     = o0;
        *(float4*)(out + (size_t)m * H_ + n0 + tx * 8 + 4) = o1;
    }
}

// ---------------------------------------------------------------------------
// Phase 2: recurrence. ROUND 12: BARRIER-FREE, WAVE-AUTONOMOUS.
//
// R7 (distributed production) was only -2%: the removed producer serial
// chain was off the critical path. Remaining step budget (3100cy): compute
// ~600, detect+distribute ~2400, where distribute = poller-reg -> LDS ->
// s_barrier -> LDS-read hop + the barrier's max-coupling over 7 pollers.
//
// This round removes the barrier AND the WG-shared h buffer entirely.
// Observation: lane l (group g=l>>3) of any wave needs ONLY slice g, rows
// cl*8..cl*8+8 (cl=l&7) -- 64B. So each lane polls its own 8 values
// DIRECTLY from the mailbox (4x dwordx4, sc0 sc1), shares them with its
// 8-lane group through a WAVE-PRIVATE LDS staging row (same-wave ds_write
// -> lgkmcnt(0) -> ds_read: no barrier; wave lockstep makes it coherent),
// then FMA + in-wave xor-tree + publish. The t-loop has ZERO s_barrier:
// waves run free; coupling is only through the tag protocol itself.
//
// Protocol (unchanged): ws[b][slot][col] = (tag<<32|bits), slot = tag&1.
// Step t consumes tag t (slot t&1), publishes tag t+1 (slot (t+1)&1).
// Lead bound now at wave granularity: a wave publishes t+2 only after
// detecting ALL of tag t+1, which requires every wave to have published
// t+1, hence consumed t -- slot reuse safe. t=0 consumes nothing (h0=0).
// Poll traffic throttled by per-chunk conditional reissue (only chunks
// with a stale tag reload). Stage rows stride 72 floats: group reads are
// 2-way bank-aliased (free, m136).
// W_reg stays asm-forced register-resident (cannot be rematerialized).
// ---------------------------------------------------------------------------
__global__ __launch_bounds__(512, 2) void rnn_rec(
    const float* __restrict__ Whh,           // [H_][H_] row-major
    float* __restrict__ out,                 // [B_][T_][H_], pre-filled XW+b
    unsigned long long* __restrict__ ws)     // [B_][2][H_] packed (tag,val)
{
    const int tid = threadIdx.x;
    const int b = blockIdx.x & 15;
    const int s = blockIdx.x >> 4;
    const int w = tid >> 6;          // wave index
    const int l = tid & 63;          // lane
    const int g = l >> 3;            // slice this lane polls / FMAs over
    const int cl = l & 7;            // column within this wave's 8
    const int c = (s << 6) + (w << 3) + cl;  // this lane's h column

    // wave-private staging: [wave][slice*72 + row]; stride 72 staggers the
    // per-group read bases across banks (2-way max aliasing = free)
    __shared__ float hstage[8][8 * 72];
    float* myst = hstage[w];

    // W slice, FORCED register-resident: W_reg[r] = Whh[g*64 + r][c].
    float W_reg[64];
    {
        const float* wbase = Whh + (size_t)(g << 6) * H_ + c;
#pragma unroll
        for (int r = 0; r < 64; ++r) {
            const float* addr = wbase + (size_t)r * H_;
            asm volatile("global_load_dword %0, %1, off"
                         : "=v"(W_reg[r]) : "v"(addr));
        }
        asm volatile("s_waitcnt vmcnt(0)" ::: "memory");
    }

    float* outb = out + (size_t)b * T_ * H_;
    unsigned long long* wsb = ws + (size_t)b * 2 * H_;

    // xw prefetch pipeline, depth 3 (lanes l<8: c == s*64+w*8+l)
    float xw0 = 0.0f, xw1 = 0.0f, xw2 = 0.0f;
    if (l < 8) {
        xw0 = outb[(size_t)0 * H_ + c];
        xw1 = outb[(size_t)1 * H_ + c];
        xw2 = outb[(size_t)2 * H_ + c];
    }

    for (int t = 0; t < T_; ++t) {
        float acc = 0.0f;
        if (t > 0) {
            const unsigned int tn = (unsigned int)t;
            // this lane's 8 needed values: slice g, rows cl*8 .. cl*8+7
            const unsigned long long* src =
                wsb + (size_t)(t & 1) * H_ + (g << 6) + (cl << 3);
            uint4v c0, c1, c2, c3;   // 4 chunks x 2 u64 (tags at .y/.w)
            asm volatile("global_load_dwordx4 %0, %1, off sc0 sc1"
                         : "=v"(c0) : "v"(src));
            asm volatile("global_load_dwordx4 %0, %1, off offset:16 sc0 sc1"
                         : "=v"(c1) : "v"(src));
            asm volatile("global_load_dwordx4 %0, %1, off offset:32 sc0 sc1"
                         : "=v"(c2) : "v"(src));
            asm volatile("global_load_dwordx4 %0, %1, off offset:48 sc0 sc1"
                         : "=v"(c3) : "v"(src));
            for (;;) {
                asm volatile("s_waitcnt vmcnt(0)"
                             : "+v"(c0), "+v"(c1), "+v"(c2), "+v"(c3)
                             :: "memory");
                __builtin_amdgcn_sched_barrier(0);
                const bool ok0 = (c0.y >= tn) & (c0.w >= tn);
                const bool ok1 = (c1.y >= tn) & (c1.w >= tn);
                const bool ok2 = (c2.y >= tn) & (c2.w >= tn);
                const bool ok3 = (c3.y >= tn) & (c3.w >= tn);
                if (__all(ok0 & ok1 & ok2 & ok3)) break;
                // reload only stale chunks (exec-masked per lane)
                if (!ok0)
                    asm volatile("global_load_dwordx4 %0, %1, off sc0 sc1"
                                 : "=v"(c0) : "v"(src));
                if (!ok1)
                    asm volatile(
                        "global_load_dwordx4 %0, %1, off offset:16 sc0 sc1"
                        : "=v"(c1) : "v"(src));
                if (!ok2)
                    asm volatile(
                        "global_load_dwordx4 %0, %1, off offset:32 sc0 sc1"
                        : "=v"(c2) : "v"(src));
                if (!ok3)
                    asm volatile(
                        "global_load_dwordx4 %0, %1, off offset:48 sc0 sc1"
                        : "=v"(c3) : "v"(src));
            }
            // stage this lane's 8 floats for its group (wave-private)
            float4 f0, f1;
            f0.x = __uint_as_float(c0.x); f0.y = __uint_as_float(c0.z);
            f0.z = __uint_as_float(c1.x); f0.w = __uint_as_float(c1.z);
            f1.x = __uint_as_float(c2.x); f1.y = __uint_as_float(c2.z);
            f1.z = __uint_as_float(c3.x); f1.w = __uint_as_float(c3.z);
            *(float4*)(myst + g * 72 + (cl << 3))     = f0;
            *(float4*)(myst + g * 72 + (cl << 3) + 4) = f1;
            // same-wave visibility: drain LDS, no barrier needed
            asm volatile("s_waitcnt lgkmcnt(0)" ::: "memory");
            __builtin_amdgcn_sched_barrier(0);
            // FMA over slice g (8-lane broadcast reads, 2-way across groups)
            const float4* hb = (const float4*)(myst + g * 72);
#pragma unroll
            for (int i = 0; i < 16; ++i) {
                const float4 h4 = hb[i];
                acc += h4.x * W_reg[4 * i + 0] + h4.y * W_reg[4 * i + 1]
                     + h4.z * W_reg[4 * i + 2] + h4.w * W_reg[4 * i + 3];
            }
        }
        // in-wave tree reduce across the 8 row-block groups
        acc += __shfl_xor(acc, 8);
        acc += __shfl_xor(acc, 16);
        acc += __shfl_xor(acc, 32);

        const unsigned int tagp = (unsigned int)(t + 1);
        unsigned long long* wpub = wsb + (size_t)((t + 1) & 1) * H_;
        if (l < 8) {
            union { unsigned int u; float f; } cv;
            cv.f = tanhf(acc + xw0);
            unsigned long long pv =
                ((unsigned long long)tagp << 32) | (unsigned long long)cv.u;
            // publish FIRST (remote pollers wait on this)
            __hip_atomic_store(wpub + c, pv, __ATOMIC_RELAXED,
                               __HIP_MEMORY_SCOPE_AGENT);
            outb[(size_t)t * H_ + c] = cv.f;  // final output (plain)
            xw0 = xw1;
            xw1 = xw2;
            xw2 = (t + 3 < T_) ? outb[(size_t)(t + 3) * H_ + c] : 0.0f;
        }
        // NO barrier: waves are autonomous; coupling is the tag protocol.
    }
}

extern "C" void kernel_launch(void* const* d_in, const int* in_sizes, int n_in,
                              void* d_out, int out_size, void* d_ws,
                              size_t ws_size, hipStream_t stream) {
    const float* x    = (const float*)d_in[0];  // [B,T,D]
    const float* Wxh  = (const float*)d_in[1];  // [D,H]
    const float* Whh  = (const float*)d_in[2];  // [H,H]
    const float* bias = (const float*)d_in[3];  // [H]
    // d_in[4] = A, unused in forward
    float* out = (float*)d_out;

    // comm buffer: [16][2][512] x 8B = 128 KB; tags must start at 0
    // (harness poisons ws with 0xAA before every launch)
    hipMemsetAsync(d_ws, 0, (size_t)B_ * 2 * H_ * sizeof(unsigned long long),
                   stream);

    dim3 ggrid(H_ / 128, (B_ * T_) / 128, 1);
    gemm_xw<<<ggrid, 256, 0, stream>>>(x, Wxh, bias, out);

    rnn_rec<<<128, 512, 0, stream>>>(Whh, out, (unsigned long long*)d_ws);
}

// Round 11
// 3255.838 us; speedup vs baseline: 1.6476x; 1.6476x over previous
//
#include <hip/hip_runtime.h>
#include <cmath>

#define B_ 16
#define T_ 2048
#define D_ 512
#define H_ 512

// ---------------------------------------------------------------------------
// ROUND 15: FUSED GEMM+RECURRENCE (single kernel).
//
// R9/R10 (single-CU, W-in-registers) aborted twice -> abandoned per
// pre-commitment; re-analysis shows its LDS-pipe cost (1024 ds_read_b128
// per CU per step) exceeded the VALU floor anyway.
//
// Base = R7 champion (2643us rnn + 252us gemm): 8 WGs x 512 thr per batch,
// distributed production, packed u64 mailbox (tag<<32|bits), agent-scope,
// double-buffered by tag&1, dependent-load poll (the only exchange
// primitive that survived 6 probes). R7 counters: VALUBusy 18.7% -> waves
// idle ~75% of each step in poll-wait.
//
// CHANGE: the standalone XW gemm (252us serial prologue) is DELETED.
// WG (b,s) computes its own xw slice in the poll bubbles:
//   * thread (w,l) pins X_reg[r] = Wxh[64g + ((grot+r)&63)][c] (same
//     rotated layout as W_reg; VGPR ~170 total, asm-pinned).
//   * x rows stream via a 4-slot LDS ring: global->reg at step t-1,
//     reg->LDS at step t (write slot (t+3)&3), consumed at step t+2 --
//     every handoff has >= 1 barrier of slack.
//   * xw for step t+1 is computed AFTER this step's publish and BEFORE
//     the poll: it lives inside the ~2400cy poll-wait bubble, off the
//     critical path. (xw_hold includes bias.)
// Recurrence datapath, mailbox protocol, and poll loop are byte-identical
// to R7. Producer lead stays bounded by the same induction.
// ---------------------------------------------------------------------------
__device__ __forceinline__ void bar_lds() {
    asm volatile("s_waitcnt lgkmcnt(0)\n\ts_barrier" ::: "memory");
}

// full-column dot of reg-pinned slice REG against LDS vector base XR
// (rotated indexing, matches the REG load layout); result -> all lanes
#define SLICE_DOT(RES, XR, REG)                                              \
    {                                                                        \
        float a_ = 0.0f;                                                     \
        _Pragma("unroll")                                                    \
        for (int i_ = 0; i_ < 16; ++i_) {                                    \
            const int idx_ = (g << 6) + ((grot + (i_ << 2)) & 63);           \
            const float4 v4_ = *(const float4*)((XR) + idx_);                \
            a_ += v4_.x * (REG)[4 * i_ + 0] + v4_.y * (REG)[4 * i_ + 1]      \
                + v4_.z * (REG)[4 * i_ + 2] + v4_.w * (REG)[4 * i_ + 3];     \
        }                                                                    \
        a_ += __shfl_xor(a_, 8);                                             \
        a_ += __shfl_xor(a_, 16);                                            \
        a_ += __shfl_xor(a_, 32);                                            \
        (RES) = a_;                                                          \
    }

__global__ __launch_bounds__(512, 2) void rnn_fused(
    const float* __restrict__ x,     // [B,T,D]
    const float* __restrict__ Wxh,   // [D,H]
    const float* __restrict__ Whh,   // [H,H]
    const float* __restrict__ bias,  // [H]
    float* __restrict__ out,         // [B,T,H]
    unsigned long long* __restrict__ ws)  // [B][2][H] packed (tag,val)
{
    const int tid = threadIdx.x;
    const int b = blockIdx.x & 15;
    const int s = blockIdx.x >> 4;
    const int w = tid >> 6;          // wave index
    const int l = tid & 63;          // lane
    const int g = l >> 3;            // part: rows 64g..64g+63 (both mats)
    const int cl = l & 7;            // column within this wave's 8
    const int c = (s << 6) + (w << 3) + cl;  // this lane's column
    const int grot = g << 3;         // bank-stagger rotation (R7-proven)

    __shared__ float h_lds[2][H_];   // double-buffered hidden state
    __shared__ float xring[4][D_];   // x-row ring, depth 4

    // Register-pinned weight slices (asm-defined: cannot be rematerialized)
    float W_reg[64];   // W_reg[r] = Whh[64g + ((grot+r)&63)][c]
    float X_reg[64];   // X_reg[r] = Wxh[64g + ((grot+r)&63)][c]
    {
#pragma unroll
        for (int r = 0; r < 64; ++r) {
            const int row = (g << 6) + ((grot + r) & 63);
            const float* addr = Whh + (size_t)row * H_ + c;
            asm volatile("global_load_dword %0, %1, off"
                         : "=v"(W_reg[r]) : "v"(addr));
        }
#pragma unroll
        for (int r = 0; r < 64; ++r) {
            const int row = (g << 6) + ((grot + r) & 63);
            const float* addr = Wxh + (size_t)row * H_ + c;
            asm volatile("global_load_dword %0, %1, off"
                         : "=v"(X_reg[r]) : "v"(addr));
        }
        asm volatile("s_waitcnt vmcnt(0)" ::: "memory");
    }

    const float* xb = x + (size_t)b * T_ * D_;
    float* outb = out + (size_t)b * T_ * H_;
    unsigned long long* wsb = ws + (size_t)b * 2 * H_;
    const float bias_c = bias[c];

    // prime x ring: rows 0..2 into slots 0..2; row 3 into the hold register
    if (tid < 128) {
#pragma unroll
        for (int r = 0; r < 3; ++r) {
            float4 v = *(const float4*)(xb + (size_t)r * D_ + tid * 4);
            *(float4*)(&xring[r][tid * 4]) = v;
        }
    }
    float4 xrow_hold = {0.f, 0.f, 0.f, 0.f};
    if (tid < 128)
        xrow_hold = *(const float4*)(xb + (size_t)3 * D_ + tid * 4);

    h_lds[0][tid] = 0.0f;  // h_0 = 0
    __syncthreads();

    // xw for t=0 (from ring slot 0)
    float xw_hold;
    SLICE_DOT(xw_hold, xring[0], X_reg);
    xw_hold += bias_c;

    // poll duty: waves 0..6 cover the 7 remote slices; wave 7 none
    const int q = (w < 7) ? (w + (w >= s ? 1 : 0)) : -1;

    for (int t = 0; t < T_; ++t) {
        // (a) x-ring stage: write row t+3 (held in reg), issue load t+4
        if (tid < 128) {
            if (t + 3 < T_)
                *(float4*)(&xring[(t + 3) & 3][tid * 4]) = xrow_hold;
            if (t + 4 < T_)
                xrow_hold =
                    *(const float4*)(xb + (size_t)(t + 4) * D_ + tid * 4);
        }

        // (b) recurrence dot over h(t) -- critical path
        float acc;
        SLICE_DOT(acc, h_lds[t & 1], W_reg);

        const unsigned int tag = (unsigned int)(t + 1);
        unsigned long long* wslot = wsb + (size_t)((t + 1) & 1) * H_;
        float* hn = h_lds[(t + 1) & 1];

        if (l < 8) {
            // produce this wave's 8 columns: tanh + publish NOW
            union { unsigned int u; float f; } cv;
            cv.f = tanhf(acc + xw_hold);  // xw_hold includes bias
            unsigned long long pv =
                ((unsigned long long)tag << 32) | (unsigned long long)cv.u;
            __hip_atomic_store(wslot + c, pv, __ATOMIC_RELAXED,
                               __HIP_MEMORY_SCOPE_AGENT);
            outb[(size_t)t * H_ + c] = cv.f;  // final output (plain)
            hn[c] = cv.f;                     // local copy, next buffer
        }

        // (c) xw for t+1 -- off critical path, fills the poll bubble
        if (t + 1 < T_) {
            float a;
            SLICE_DOT(a, xring[(t + 1) & 3], X_reg);
            xw_hold = a + bias_c;
        }

        // (d) gather one remote slice into the next h buffer (R7 poll)
        if (q >= 0) {
            unsigned long long* src = wslot + (q << 6) + l;
            unsigned long long v;
            do {
                v = __hip_atomic_load(src, __ATOMIC_RELAXED,
                                      __HIP_MEMORY_SCOPE_AGENT);
            } while ((unsigned int)(v >> 32) < tag);
            union { unsigned int u; float f; } cv2;
            cv2.u = (unsigned int)v;
            hn[(q << 6) + l] = cv2.f;
        }

        bar_lds();  // single barrier: h(t+1) + staged x row complete
    }
}

extern "C" void kernel_launch(void* const* d_in, const int* in_sizes, int n_in,
                              void* d_out, int out_size, void* d_ws,
                              size_t ws_size, hipStream_t stream) {
    const float* x    = (const float*)d_in[0];  // [B,T,D]
    const float* Wxh  = (const float*)d_in[1];  // [D,H]
    const float* Whh  = (const float*)d_in[2];  // [H,H]
    const float* bias = (const float*)d_in[3];  // [H]
    // d_in[4] = A, unused in forward
    float* out = (float*)d_out;

    // mailbox: [16][2][512] x 8B = 128 KB; tags must start at 0
    // (harness poisons ws with 0xAA before every launch)
    hipMemsetAsync(d_ws, 0, (size_t)B_ * 2 * H_ * sizeof(unsigned long long),
                   stream);

    rnn_fused<<<128, 512, 0, stream>>>(x, Wxh, Whh, bias, out,
                                       (unsigned long long*)d_ws);
}